// Round 13
// baseline (155.688 us; speedup 1.0000x reference)
//
#include <hip/hip_runtime.h>

#define E_EDGES 160000
#define N_NODES 10000
#define SLOTS   32      // per-node bucket capacity; overflow falls back to atomics

// 24^(-0.5)
#define TEMP 0.20412414523193154f

typedef __fp16 half2_t __attribute__((ext_vector_type(2)));
typedef __fp16 half8_t __attribute__((ext_vector_type(8)));
typedef float f32x4 __attribute__((ext_vector_type(4)));

__device__ __forceinline__ float fdot2(half2_t a, half2_t b, float c) {
#if __has_builtin(__builtin_amdgcn_fdot2)
    return __builtin_amdgcn_fdot2(a, b, c, false);
#else
    return fmaf((float)a.x, (float)b.x, fmaf((float)a.y, (float)b.y, c));
#endif
}
__device__ __forceinline__ half2_t pk(float a, float b) {
    return __builtin_amdgcn_cvt_pkrtz(a, b);
}

// prep: W2 [768][64] f32 -> f16 A-frag order; W1 [64][32] -> f16 A-frag order
// with row permutation so Phase-A MFMA output lands in conv B-frag order;
// zero cnt + num/den.
__global__ __launch_bounds__(256)
void prep_kernel(const float* __restrict__ W2, const float* __restrict__ W1,
                 unsigned* __restrict__ w2p, uint4* __restrict__ w1pk,
                 int* __restrict__ cnt, float4* __restrict__ zbuf)
{
    int u = blockIdx.x * blockDim.x + threadIdx.x;   // u < 24576
    if (u < N_NODES) cnt[u] = 0;
    // zero num (N*24) + den (N*4) = 70000 float4 (contiguous)
    #pragma unroll
    for (int i = 0; i < 3; ++i) {
        int z = u + i * 24576;
        if (z < (N_NODES * 28) / 4) zbuf[z] = make_float4(0.f, 0.f, 0.f, 0.f);
    }
    // W1 pack: tile t (0..3), lane l: A-frag row r16=l&15, k-chunk q=l>>4.
    if (u < 256) {
        int t = u >> 6, l = u & 63;
        int r16 = l & 15, q = l >> 4;
        int row = 32*(t >> 1) + ((r16 >> 2) << 3) + ((t & 1) << 2) + (r16 & 3);
        union { __fp16 h[8]; uint4 v; } o2;
        #pragma unroll
        for (int i = 0; i < 8; ++i) o2.h[i] = (__fp16)W1[row*32 + q*8 + i];
        w1pk[(t << 6) + l] = o2.v;
    }
    int tp    = u & 3;
    int lane  = (u >> 2) & 63;
    int piece = (u >> 8) & 3;
    int c     = u >> 10;
    int em = lane & 15, quad = lane >> 4;
    int row = 32*c + ((piece >> 1) << 4) + em;
    int col = ((piece & 1) << 5) + quad*8 + 2*tp;
    union { half2_t h; unsigned v; } o;
    o.h.x = (__fp16)W2[row*64 + col];
    o.h.y = (__fp16)W2[row*64 + col + 1];
    w2p[u] = o.v;
}

// 4-MFMA quartet + dot tail: produces the 3 conv components (replicated in
// all lanes after the shfl reduce) for one c-row, one edge-batch.
#define MFMA4_TAIL(F0,F1,F2,F3,HL,HH,BB0,BB1,T2,P0,P1,P2) { \
    f32x4 a0 = {(BB0).x, (BB0).y, (BB0).z, (BB0).w}; \
    a0 = __builtin_amdgcn_mfma_f32_16x16x32_f16((F0), (HL), a0, 0, 0, 0); \
    a0 = __builtin_amdgcn_mfma_f32_16x16x32_f16((F1), (HH), a0, 0, 0, 0); \
    f32x4 a1 = {(BB1).x, (BB1).y, (BB1).z, (BB1).w}; \
    a1 = __builtin_amdgcn_mfma_f32_16x16x32_f16((F2), (HL), a1, 0, 0, 0); \
    a1 = __builtin_amdgcn_mfma_f32_16x16x32_f16((F3), (HH), a1, 0, 0, 0); \
    P0 = 0.f; P1 = 0.f; P2 = 0.f; \
    _Pragma("unroll") \
    for (int r = 0; r < 4; ++r) { \
        half2_t rp = pk(a0[r], a1[r]); \
        P0 = fdot2(rp, (T2)[r][0], P0); \
        P1 = fdot2(rp, (T2)[r][1], P1); \
        P2 = fdot2(rp, (T2)[r][2], P2); \
    } \
    P0 += __shfl_xor(P0, 16); P0 += __shfl_xor(P0, 32); \
    P1 += __shfl_xor(P1, 16); P1 += __shfl_xor(P1, 32); \
    P2 += __shfl_xor(P2, 16); P2 += __shfl_xor(P2, 32); \
}

// Phase A: h = relu(W1 @ x + b1) via 4 MFMAs, C-init = bias.
#define PHASE_A(XB, HLO, HHI) { \
    f32x4 ha0 = {b1a.x, b1a.y, b1a.z, b1a.w}; \
    f32x4 ha1 = {b1b.x, b1b.y, b1b.z, b1b.w}; \
    f32x4 ha2 = {b1c.x, b1c.y, b1c.z, b1c.w}; \
    f32x4 ha3 = {b1d.x, b1d.y, b1d.z, b1d.w}; \
    ha0 = __builtin_amdgcn_mfma_f32_16x16x32_f16(w1f[0], (XB), ha0, 0, 0, 0); \
    ha1 = __builtin_amdgcn_mfma_f32_16x16x32_f16(w1f[1], (XB), ha1, 0, 0, 0); \
    ha2 = __builtin_amdgcn_mfma_f32_16x16x32_f16(w1f[2], (XB), ha2, 0, 0, 0); \
    ha3 = __builtin_amdgcn_mfma_f32_16x16x32_f16(w1f[3], (XB), ha3, 0, 0, 0); \
    union { half2_t h2[4]; half8_t v; } lo, hi; \
    lo.h2[0] = pk(fmaxf(ha0[0],0.f), fmaxf(ha0[1],0.f)); \
    lo.h2[1] = pk(fmaxf(ha0[2],0.f), fmaxf(ha0[3],0.f)); \
    lo.h2[2] = pk(fmaxf(ha1[0],0.f), fmaxf(ha1[1],0.f)); \
    lo.h2[3] = pk(fmaxf(ha1[2],0.f), fmaxf(ha1[3],0.f)); \
    hi.h2[0] = pk(fmaxf(ha2[0],0.f), fmaxf(ha2[1],0.f)); \
    hi.h2[1] = pk(fmaxf(ha2[2],0.f), fmaxf(ha2[3],0.f)); \
    hi.h2[2] = pk(fmaxf(ha3[0],0.f), fmaxf(ha3[1],0.f)); \
    hi.h2[3] = pk(fmaxf(ha3[2],0.f), fmaxf(ha3[3],0.f)); \
    (HLO) = lo.v; (HHI) = hi.v; \
}

// Phase B: equivariant tmp2 quarter for edge E -> T2OUT[4][3] (half2 pairs)
#define PHASE_B(E, T2OUT) { \
    float bas[18]; \
    const float2* bv = (const float2*)(basis + (size_t)(E) * 18); \
    _Pragma("unroll") \
    for (int i = 0; i < 9; ++i) { float2 t = bv[i]; bas[2*i] = t.x; bas[2*i+1] = t.y; } \
    const float* fp = f + (size_t)src[(E)] * 48 + quad*6; \
    float fl[6], fh[6]; \
    _Pragma("unroll") \
    for (int i = 0; i < 3; ++i) { \
        float2 a = *(const float2*)(fp + 2*i);      fl[2*i] = a.x; fl[2*i+1] = a.y; \
        float2 b = *(const float2*)(fp + 24 + 2*i); fh[2*i] = b.x; fh[2*i+1] = b.y; \
    } \
    _Pragma("unroll") \
    for (int jj = 0; jj < 4; ++jj) { \
        const int mr = (jj >> 1) * 3; \
        const int rb = (jj & 1) * 3; \
        _Pragma("unroll") \
        for (int d = 0; d < 3; ++d) { \
            float lo = fmaf(fl[mr+0], bas[rb+d], \
                       fmaf(fl[mr+1], bas[6+rb+d], fl[mr+2] * bas[12+rb+d])); \
            float hi = fmaf(fh[mr+0], bas[rb+d], \
                       fmaf(fh[mr+1], bas[6+rb+d], fh[mr+2] * bas[12+rb+d])); \
            (T2OUT)[jj][d] = pk(lo, hi); \
        } \
    } \
}

// epilogue: 64 B bucket record (4 x 16 B stores) or rare atomic fallback
#define EPILOGUE(PB, DNB, VREG, EXV) { \
    if ((PB) < SLOTS) { \
        unsigned char* rec = bkt + ((size_t)(DNB) * SLOTS + (PB)) * 64; \
        if (quad == 3) { \
            *(float4*)(rec + 48) = make_float4((EXV)[0], (EXV)[1], (EXV)[2], (EXV)[3]); \
        } else { \
            union { half2_t h2[4]; uint4 u; } pv; \
            if (quad == 0) { \
                pv.h2[0] = pk((VREG)[0][0], (VREG)[0][1]); \
                pv.h2[1] = pk((VREG)[0][2], (VREG)[1][0]); \
                pv.h2[2] = pk((VREG)[1][1], (VREG)[1][2]); \
                pv.h2[3] = pk((VREG)[2][0], (VREG)[2][1]); \
            } else if (quad == 1) { \
                pv.h2[0] = pk((VREG)[2][2], (VREG)[3][0]); \
                pv.h2[1] = pk((VREG)[3][1], (VREG)[3][2]); \
                pv.h2[2] = pk((VREG)[4][0], (VREG)[4][1]); \
                pv.h2[3] = pk((VREG)[4][2], (VREG)[5][0]); \
            } else { \
                pv.h2[0] = pk((VREG)[5][1], (VREG)[5][2]); \
                pv.h2[1] = pk((VREG)[6][0], (VREG)[6][1]); \
                pv.h2[2] = pk((VREG)[6][2], (VREG)[7][0]); \
                pv.h2[3] = pk((VREG)[7][1], (VREG)[7][2]); \
            } \
            *(uint4*)(rec + quad*16) = pv.u; \
        } \
    } else { \
        float* nb = num + (size_t)(DNB) * 24; \
        if (quad == 0) { \
            atomicAdd(nb+0, (EXV)[0]*(VREG)[0][0]); atomicAdd(nb+1, (EXV)[0]*(VREG)[0][1]); \
            atomicAdd(nb+2, (EXV)[0]*(VREG)[0][2]); atomicAdd(nb+3, (EXV)[0]*(VREG)[1][0]); \
            atomicAdd(nb+4, (EXV)[0]*(VREG)[1][1]); atomicAdd(nb+5, (EXV)[0]*(VREG)[1][2]); \
            atomicAdd(nb+6, (EXV)[1]*(VREG)[2][0]); atomicAdd(nb+7, (EXV)[1]*(VREG)[2][1]); \
        } else if (quad == 1) { \
            atomicAdd(nb+8,  (EXV)[1]*(VREG)[2][2]); atomicAdd(nb+9,  (EXV)[1]*(VREG)[3][0]); \
            atomicAdd(nb+10, (EXV)[1]*(VREG)[3][1]); atomicAdd(nb+11, (EXV)[1]*(VREG)[3][2]); \
            atomicAdd(nb+12, (EXV)[2]*(VREG)[4][0]); atomicAdd(nb+13, (EXV)[2]*(VREG)[4][1]); \
            atomicAdd(nb+14, (EXV)[2]*(VREG)[4][2]); atomicAdd(nb+15, (EXV)[2]*(VREG)[5][0]); \
        } else if (quad == 2) { \
            atomicAdd(nb+16, (EXV)[2]*(VREG)[5][1]); atomicAdd(nb+17, (EXV)[2]*(VREG)[5][2]); \
            atomicAdd(nb+18, (EXV)[3]*(VREG)[6][0]); atomicAdd(nb+19, (EXV)[3]*(VREG)[6][1]); \
            atomicAdd(nb+20, (EXV)[3]*(VREG)[6][2]); atomicAdd(nb+21, (EXV)[3]*(VREG)[7][0]); \
            atomicAdd(nb+22, (EXV)[3]*(VREG)[7][1]); atomicAdd(nb+23, (EXV)[3]*(VREG)[7][2]); \
        } else { \
            float* db = den + (size_t)(DNB) * 4; \
            atomicAdd(db+0, (EXV)[0]); atomicAdd(db+1, (EXV)[1]); \
            atomicAdd(db+2, (EXV)[2]); atomicAdd(db+3, (EXV)[3]); \
        } \
    } \
}

// ---- fused per-edge kernel v3: 256-thread blocks, 2 edges/thread
// (128 edges/block, grid 1250). k-group AND q-group co-resident in 64 KB LDS
// -> fused kq pass with NO kreg array and no barrier between k and q.
// 3 barriers per 128 edges (was 5 per 64). v staged into the k region.
__global__ __launch_bounds__(256, 2)
void fused_kernel(const int* __restrict__ src, const int* __restrict__ dst,
                  const float* __restrict__ basis, const float* __restrict__ efeat,
                  const float* __restrict__ f,
                  const uint4* __restrict__ w1pk, const float* __restrict__ b1,
                  const uint4* __restrict__ w2p, const float* __restrict__ b2,
                  unsigned char* __restrict__ bkt, int* __restrict__ cnt,
                  float* __restrict__ num, float* __restrict__ den)
{
    __shared__ __fp16 w2s[2*16384];     // 64 KB: [0]=k (later v), [16384]=q
    __shared__ float  b2s[768];         // 3 KB

    const int tid  = threadIdx.x;
    const int lane = tid & 63;
    const int wid  = tid >> 6;
    const int em   = lane & 15;
    const int quad = lane >> 4;
    const int base = (blockIdx.x * 4 + wid) * 32;
    const int e0 = base + em;
    const int e1 = base + 16 + em;

    // ---- stage k-group + q-group (16 uint4/thread) + b2 ----
    {
        uint4* d4 = (uint4*)w2s;
        #pragma unroll
        for (int i = 0; i < 8; ++i) d4[i*256 + tid] = w2p[i*256 + tid];
        #pragma unroll
        for (int i = 0; i < 8; ++i) d4[2048 + i*256 + tid] = w2p[2048 + i*256 + tid];
        if (tid < 192) ((float4*)b2s)[tid] = ((const float4*)b2)[tid];
    }

    // ---- bucket placement: quad0 handles e0, quad1 handles e1 ----
    int p_slot = 0, dn0 = 0;
    if (quad == 0) {
        dn0 = dst[e0];
        p_slot = atomicAdd(&cnt[dn0], 1);
    } else if (quad == 1) {
        dn0 = dst[e1];
        p_slot = atomicAdd(&cnt[dn0], 1);
    }
    const int pb0  = __shfl(p_slot, em);
    const int dnb0 = __shfl(dn0, em);
    const int pb1  = __shfl(p_slot, 16 + em);
    const int dnb1 = __shfl(dn0, 16 + em);

    // ---- W1 A-fragments + bias ----
    half8_t w1f[4];
    #pragma unroll
    for (int t = 0; t < 4; ++t) {
        union { uint4 u; half8_t v; } c;
        c.u = w1pk[(t << 6) + lane];
        w1f[t] = c.v;
    }
    float4 b1a = *(const float4*)(b1 + quad*8);
    float4 b1b = *(const float4*)(b1 + quad*8 + 4);
    float4 b1c = *(const float4*)(b1 + 32 + quad*8);
    float4 b1d = *(const float4*)(b1 + 32 + quad*8 + 4);

    // ---- x B-fragments for both edge batches ----
    half8_t xb0, xb1;
    {
        const float4* xv = (const float4*)(efeat + (size_t)e0 * 32 + quad*8);
        float4 x0 = xv[0], x1 = xv[1];
        union { half2_t h2[4]; half8_t v; } xu;
        xu.h2[0] = pk(x0.x, x0.y); xu.h2[1] = pk(x0.z, x0.w);
        xu.h2[2] = pk(x1.x, x1.y); xu.h2[3] = pk(x1.z, x1.w);
        xb0 = xu.v;
        const float4* yv = (const float4*)(efeat + (size_t)e1 * 32 + quad*8);
        float4 y0 = yv[0], y1 = yv[1];
        xu.h2[0] = pk(y0.x, y0.y); xu.h2[1] = pk(y0.z, y0.w);
        xu.h2[2] = pk(y1.x, y1.y); xu.h2[3] = pk(y1.z, y1.w);
        xb1 = xu.v;
    }

    // ---- Phase A both batches (register-only; overlaps staging) ----
    half8_t h_lo0, h_hi0, h_lo1, h_hi1;
    PHASE_A(xb0, h_lo0, h_hi0);
    PHASE_A(xb1, h_lo1, h_hi1);

    // ---- Phase B both batches ----
    half2_t t20[4][3], t21[4][3];
    PHASE_B(e0, t20);
    PHASE_B(e1, t21);

    __syncthreads();   // barrier 1: k+q staged

    // ---- fused kq pass: per cg, k row cg and q row 8+cg, both batches;
    //      kreg never materializes ----
    float sreg0[4], sreg1[4];
    #pragma unroll
    for (int cg = 0; cg < 8; ++cg) {
        const __fp16* kp = w2s + ((cg*4)*64 + lane)*8;
        half8_t kf0 = *(const half8_t*)(kp);
        half8_t kf1 = *(const half8_t*)(kp + 512);
        half8_t kf2 = *(const half8_t*)(kp + 1024);
        half8_t kf3 = *(const half8_t*)(kp + 1536);
        const __fp16* qp = kp + 16384;
        half8_t qf0 = *(const half8_t*)(qp);
        half8_t qf1 = *(const half8_t*)(qp + 512);
        half8_t qf2 = *(const half8_t*)(qp + 1024);
        half8_t qf3 = *(const half8_t*)(qp + 1536);
        float4 bk0 = *(const float4*)(b2s + 32*cg + quad*4);
        float4 bk1 = *(const float4*)(b2s + 32*cg + 16 + quad*4);
        float4 bq0 = *(const float4*)(b2s + 32*(8+cg) + quad*4);
        float4 bq1 = *(const float4*)(b2s + 32*(8+cg) + 16 + quad*4);
        float k0, k1, k2, q0, q1, q2, s_;
        // batch 0
        MFMA4_TAIL(kf0,kf1,kf2,kf3, h_lo0,h_hi0, bk0,bk1, t20, k0,k1,k2);
        MFMA4_TAIL(qf0,qf1,qf2,qf3, h_lo0,h_hi0, bq0,bq1, t20, q0,q1,q2);
        s_ = q0*k0 + q1*k1 + q2*k2;
        if ((cg & 1) == 0) sreg0[cg>>1] = s_; else sreg0[cg>>1] += s_;
        // batch 1
        MFMA4_TAIL(kf0,kf1,kf2,kf3, h_lo1,h_hi1, bk0,bk1, t21, k0,k1,k2);
        MFMA4_TAIL(qf0,qf1,qf2,qf3, h_lo1,h_hi1, bq0,bq1, t21, q0,q1,q2);
        s_ = q0*k0 + q1*k1 + q2*k2;
        if ((cg & 1) == 0) sreg1[cg>>1] = s_; else sreg1[cg>>1] += s_;
    }

    // exp(leaky_relu(s*temp)); no max subtraction (verified R2-R12)
    float exv0[4], exv1[4];
    #pragma unroll
    for (int hh = 0; hh < 4; ++hh) {
        float s = sreg0[hh] * TEMP;
        s = (s > 0.0f) ? s : 0.2f * s;
        exv0[hh] = __expf(s);
        float t = sreg1[hh] * TEMP;
        t = (t > 0.0f) ? t : 0.2f * t;
        exv1[hh] = __expf(t);
    }

    __syncthreads();   // barrier 2: all reads of k region done

    // ---- stage v-group into the k region (8 uint4/thread) ----
    {
        uint4* d4 = (uint4*)w2s;
        #pragma unroll
        for (int i = 0; i < 8; ++i) d4[i*256 + tid] = w2p[4096 + i*256 + tid];
    }

    __syncthreads();   // barrier 3: v staged

    // ---- v pass, batch 0 sweep + epilogue, then batch 1 ----
    {
        float vreg[8][3];
        #pragma unroll
        for (int cg = 0; cg < 8; ++cg) {
            const __fp16* vp = w2s + ((cg*4)*64 + lane)*8;
            half8_t vf0 = *(const half8_t*)(vp);
            half8_t vf1 = *(const half8_t*)(vp + 512);
            half8_t vf2 = *(const half8_t*)(vp + 1024);
            half8_t vf3 = *(const half8_t*)(vp + 1536);
            float4 bv0 = *(const float4*)(b2s + 32*(16+cg) + quad*4);
            float4 bv1 = *(const float4*)(b2s + 32*(16+cg) + 16 + quad*4);
            MFMA4_TAIL(vf0,vf1,vf2,vf3, h_lo0,h_hi0, bv0,bv1, t20,
                       vreg[cg][0], vreg[cg][1], vreg[cg][2]);
        }
        EPILOGUE(pb0, dnb0, vreg, exv0);
    }
    {
        float vreg[8][3];
        #pragma unroll
        for (int cg = 0; cg < 8; ++cg) {
            const __fp16* vp = w2s + ((cg*4)*64 + lane)*8;
            half8_t vf0 = *(const half8_t*)(vp);
            half8_t vf1 = *(const half8_t*)(vp + 512);
            half8_t vf2 = *(const half8_t*)(vp + 1024);
            half8_t vf3 = *(const half8_t*)(vp + 1536);
            float4 bv0 = *(const float4*)(b2s + 32*(16+cg) + quad*4);
            float4 bv1 = *(const float4*)(b2s + 32*(16+cg) + 16 + quad*4);
            MFMA4_TAIL(vf0,vf1,vf2,vf3, h_lo1,h_hi1, bv0,bv1, t21,
                       vreg[cg][0], vreg[cg][1], vreg[cg][2]);
        }
        EPILOGUE(pb1, dnb1, vreg, exv1);
    }
}

// ---- gather: R9-proven v1. One wave per node; contiguous 64 B records ----
__global__ __launch_bounds__(256)
void gather_kernel(const int* __restrict__ cnt, const unsigned char* __restrict__ bkt,
                   const float* __restrict__ num, const float* __restrict__ den,
                   float* __restrict__ out)
{
    const int lane = threadIdx.x & 63;
    const int wid  = threadIdx.x >> 6;
    const int n = blockIdx.x * 4 + wid;
    if (n >= N_NODES) return;
    int deg = cnt[n];
    if (deg > SLOTS) deg = SLOTS;
    const unsigned char* rec = bkt + (size_t)n * SLOTS * 64;

    const int j = lane & 31;            // output component (j < 24)
    const int half = lane >> 5;         // slot-range split
    const int hd = (j < 24) ? (j / 6) : 0;

    float acc = 0.f, dn_ = 0.f;
    if (j < 24 && half == 0) {          // merge rare overflow contributions
        acc = num[n*24 + j];
        dn_ = den[n*4 + hd];
    }
    if (j < 24) {
        #pragma unroll 2
        for (int i = half; i < deg; i += 2) {
            const unsigned char* r = rec + (size_t)i * 64;
            float ex = *(const float*)(r + 48 + hd*4);
            float v  = (float)*(const __fp16*)(r + j*2);
            dn_ += ex;
            acc = fmaf(ex, v, acc);
        }
    }
    acc += __shfl_xor(acc, 32);
    dn_ += __shfl_xor(dn_, 32);
    if (half == 0 && j < 24) {
        out[n*24 + j] = (dn_ > 0.f) ? (acc / dn_) : 0.f;
    }
}

extern "C" void kernel_launch(void* const* d_in, const int* in_sizes, int n_in,
                              void* d_out, int out_size, void* d_ws, size_t ws_size,
                              hipStream_t stream)
{
    const int*   src   = (const int*)d_in[0];
    const int*   dst   = (const int*)d_in[1];
    const float* basis = (const float*)d_in[2];
    const float* ef    = (const float*)d_in[3];
    const float* f     = (const float*)d_in[4];
    const float* W1    = (const float*)d_in[5];
    const float* b1    = (const float*)d_in[6];
    const float* W2    = (const float*)d_in[7];
    const float* b2    = (const float*)d_in[8];
    float* out = (float*)d_out;

    // workspace (~21.75 MB total; proven budget)
    unsigned char* bkt = (unsigned char*)d_ws;                      // N*SLOTS*64 B (20.48 MB)
    float* num = (float*)(bkt + (size_t)N_NODES * SLOTS * 64);      // N*24 f32 (0.96 MB)
    float* den = num + (size_t)N_NODES * 24;                        // N*4 f32 (0.16 MB)
    unsigned* w2p = (unsigned*)(den + (size_t)N_NODES * 4);         // 24576 u32 (96 KB)
    int* cnt = (int*)(w2p + 24576);                                 // N int (40 KB)
    uint4* w1pk = (uint4*)(cnt + N_NODES);                          // 256 uint4 (4 KB)

    prep_kernel<<<96, 256, 0, stream>>>(W2, W1, w2p, w1pk, cnt, (float4*)num);

    fused_kernel<<<E_EDGES / 128, 256, 0, stream>>>(src, dst, basis, ef, f,
                                                    w1pk, b1, (const uint4*)w2p, b2,
                                                    bkt, cnt, num, den);

    gather_kernel<<<(N_NODES + 3) / 4, 256, 0, stream>>>(cnt, bkt, num, den, out);
}